// Round 4
// baseline (288.495 us; speedup 1.0000x reference)
//
#include <hip/hip_runtime.h>
#include <math.h>

extern "C" __device__ float __ocml_native_exp2_f32(float);

namespace {

typedef __attribute__((ext_vector_type(8))) short short8;   // 8 bf16 = 4 VGPRs
typedef __attribute__((ext_vector_type(4))) short short4b;  // 4 bf16 = 8B store
typedef __attribute__((ext_vector_type(4))) float floatx4;  // MFMA C/D frag

constexpr int B_ = 2;
constexpr int S_ = 2048;
constexpr int DM_ = 1024;
constexpr int NH_ = 16;
constexpr int HD_ = 64;

// fp32 -> bf16 round-to-nearest-even
__device__ inline unsigned short f2bf(float f) {
  unsigned u = __builtin_bit_cast(unsigned, f);
  u += 0x7fffu + ((u >> 16) & 1u);
  return (unsigned short)(u >> 16);
}

// async global->LDS, 16B per lane; lds dest must be wave-uniform (lane i lands
// at lds + i*16).
__device__ inline void gl2lds16(const unsigned short* g, unsigned short* l) {
  __builtin_amdgcn_global_load_lds(
      (const __attribute__((address_space(1))) unsigned int*)g,
      (__attribute__((address_space(3))) unsigned int*)l, 16, 0, 0);
}

// ---------------------------------------------------------------------------
__global__ void cvt_bf16(const float* __restrict__ in,
                         unsigned short* __restrict__ out, int n8) {
  const int i = blockIdx.x * blockDim.x + threadIdx.x;
  if (i >= n8) return;
  const float4 a = ((const float4*)in)[i * 2];
  const float4 b = ((const float4*)in)[i * 2 + 1];
  short8 v;
  v[0] = (short)f2bf(a.x); v[1] = (short)f2bf(a.y);
  v[2] = (short)f2bf(a.z); v[3] = (short)f2bf(a.w);
  v[4] = (short)f2bf(b.x); v[5] = (short)f2bf(b.y);
  v[6] = (short)f2bf(b.z); v[7] = (short)f2bf(b.w);
  ((short8*)out)[i] = v;
}

// ---------------------------------------------------------------------------
__global__ void lengths_kernel(const unsigned char* __restrict__ mask,
                               int* __restrict__ lengths) {
  const int es1 = (mask[1] != 0);  // byte-1 nonzero => 1-byte bool storage
  const int b = blockIdx.x;
  __shared__ int cnt;
  if (threadIdx.x == 0) cnt = 0;
  __syncthreads();
  int local = 0;
  for (int s = threadIdx.x; s < S_; s += blockDim.x) {
    bool nz;
    if (es1) nz = mask[b * S_ + s] != 0;
    else     nz = ((const unsigned int*)mask)[b * S_ + s] != 0;
    local += nz ? 1 : 0;
  }
  atomicAdd(&cnt, local);
  __syncthreads();
  if (threadIdx.x == 0) lengths[b] = cnt;
}

// ---------------------------------------------------------------------------
// QKV GEMM (bf16 MFMA): C[m][n] = sum_k A[m][k] * W[n][k]
// M=4096, N=3072, K=1024. 128x128 tile, BK=32, 4 waves each 64x64.
// Coalesced epilogues: Q/K via swapped MFMA operands (RoPE in-register,
// 8B packed stores), V via packed 8B stores into V^T.
// NOTE: q is pre-scaled by 1/sqrt(64) * log2(e) so flash softmax can run in
// base-2 (v_exp_f32 directly, no per-element multiply).
// ---------------------------------------------------------------------------
__global__ __launch_bounds__(256) void qkv_gemm(
    const unsigned short* __restrict__ A, const unsigned short* __restrict__ W,
    const int* __restrict__ pos_xyz,
    unsigned short* __restrict__ Qb, unsigned short* __restrict__ Kb,
    unsigned short* __restrict__ Vtb) {
  __shared__ __align__(16) unsigned short As[128 * 32];
  __shared__ __align__(16) unsigned short Bs[128 * 32];
  const int m0 = blockIdx.y * 128, n0 = blockIdx.x * 128;
  const int w = threadIdx.x >> 6, lane = threadIdx.x & 63;
  const int lm = lane & 15, q4 = lane >> 4;
  const int srow = w * 32;                  // this wave's staging rows
  const int r_in = lane >> 2, c_in = (lane & 3) * 8;
  const int wr = (w >> 1) * 64, wc = (w & 1) * 64;
  const int which = n0 >> 10;               // 0=Q 1=K 2=V (block-uniform)
  floatx4 acc[4][4];
  const floatx4 z4 = {0.f, 0.f, 0.f, 0.f};
#pragma unroll
  for (int i = 0; i < 4; i++)
#pragma unroll
    for (int j = 0; j < 4; j++) acc[i][j] = z4;

  for (int k0 = 0; k0 < DM_; k0 += 32) {
    gl2lds16(A + (size_t)(m0 + srow + r_in) * DM_ + k0 + c_in, As + srow * 32);
    gl2lds16(A + (size_t)(m0 + srow + 16 + r_in) * DM_ + k0 + c_in,
             As + (srow + 16) * 32);
    gl2lds16(W + (size_t)(n0 + srow + r_in) * DM_ + k0 + c_in, Bs + srow * 32);
    gl2lds16(W + (size_t)(n0 + srow + 16 + r_in) * DM_ + k0 + c_in,
             Bs + (srow + 16) * 32);
    __syncthreads();
    short8 af[4], bf[4];
#pragma unroll
    for (int t = 0; t < 4; t++)
      af[t] = *(const short8*)(As + (wr + t * 16 + lm) * 32 + q4 * 8);
#pragma unroll
    for (int t = 0; t < 4; t++)
      bf[t] = *(const short8*)(Bs + (wc + t * 16 + lm) * 32 + q4 * 8);
    if (which == 2) {
      // acc[mt][nt]: row <-> m(si), col <-> n(d)
#pragma unroll
      for (int i = 0; i < 4; i++)
#pragma unroll
        for (int j = 0; j < 4; j++)
          acc[i][j] = __builtin_amdgcn_mfma_f32_16x16x32_bf16(af[i], bf[j],
                                                              acc[i][j], 0, 0, 0);
    } else {
      // swapped: acc[nt][mt]: row <-> n(d), col <-> m(si)
#pragma unroll
      for (int i = 0; i < 4; i++)
#pragma unroll
        for (int j = 0; j < 4; j++)
          acc[i][j] = __builtin_amdgcn_mfma_f32_16x16x32_bf16(bf[i], af[j],
                                                              acc[i][j], 0, 0, 0);
    }
    __syncthreads();
  }

  const int h = ((n0 + wc) & 1023) >> 6;  // wave-uniform head
  if (which == 2) {
#pragma unroll
    for (int nt = 0; nt < 4; nt++) {
      const int d = nt * 16 + lm;
#pragma unroll
      for (int mt = 0; mt < 4; mt++) {
        const int m = m0 + wr + mt * 16 + q4 * 4;
        const int bi = m >> 11, si = m & (S_ - 1);
        short4b pk;
#pragma unroll
        for (int r = 0; r < 4; r++) pk[r] = (short)f2bf(acc[mt][nt][r]);
        *(short4b*)(Vtb + ((size_t)(bi * NH_ + h) * HD_ + d) * S_ + si) = pk;
      }
    }
  } else {
    unsigned short* Dst = (which == 0) ? Qb : Kb;
    // q pre-scaled by 1/8 * log2(e) for base-2 flash softmax
    const float osc = (which == 0) ? 0.125f * 1.44269504088896f : 1.0f;
#pragma unroll
    for (int nt = 0; nt < 4; nt++) {
      const int dbase = nt * 16 + q4 * 4;  // even; both RoPE pairs in-register
      const int p0 = dbase >> 1;           // even -> p0,p0+1 share an axis
      int axis, j0, dseg;
      if (p0 < 10)      { axis = 0; j0 = p0;      dseg = 20; }
      else if (p0 < 20) { axis = 1; j0 = p0 - 10; dseg = 20; }
      else              { axis = 2; j0 = p0 - 20; dseg = 24; }
      // 10000^(-2j/dseg) = exp(-2j/dseg * ln 1e4)
      const float invf0 =
          __expf(-(2.0f * (float)j0 / (float)dseg) * 9.210340371976184f);
      const float invf1 =
          __expf(-(2.0f * (float)(j0 + 1) / (float)dseg) * 9.210340371976184f);
#pragma unroll
      for (int mt = 0; mt < 4; mt++) {
        const int m = m0 + wr + mt * 16 + lm;
        const int bi = m >> 11, si = m & (S_ - 1);
        const int pos = pos_xyz[((size_t)bi * S_ + si) * 3 + axis];
        short4b pk;
#pragma unroll
        for (int u = 0; u < 2; u++) {
          const float ve = acc[nt][mt][2 * u], vo = acc[nt][mt][2 * u + 1];
          float sn, cs;
          sincosf((float)pos * (u ? invf1 : invf0), &sn, &cs);
          pk[2 * u]     = (short)f2bf(fmaf(ve, cs, -vo * sn) * osc);
          pk[2 * u + 1] = (short)f2bf(fmaf(vo, cs, ve * sn) * osc);
        }
        *(short4b*)(Dst + ((size_t)(bi * NH_ + h) * S_ + si) * HD_ + dbase) = pk;
      }
    }
  }
}

// ---------------------------------------------------------------------------
// Flash attention on MFMA. Block = (64 q-rows) x (b,h); 4 waves, each owns a
// 16-row q strip. K/V double-buffered in XOR-swizzled LDS via global_load_lds
// (prefetch at top of iter, drain at end-of-iter barrier). Softmax in base-2
// (q pre-scaled by log2 e). Masking only on diagonal/len-tail tiles
// (wave-uniform branch). Ps: stride 64 + chunk-XOR swizzle -> LDS = exactly
// 40960 B -> 4 blocks/CU -> the whole 1024-block grid is co-resident (no
// tail). Consecutive blocks get complementary qt (work pairing).
// ---------------------------------------------------------------------------
__global__ __launch_bounds__(256) void flash_mfma(
    const unsigned short* __restrict__ Q, const unsigned short* __restrict__ Kg,
    const unsigned short* __restrict__ Vt, const int* __restrict__ lengths,
    unsigned short* __restrict__ Oa) {
  __shared__ __align__(16) unsigned short Ks[2 * 64 * 64];
  __shared__ __align__(16) unsigned short Vs[2 * 64 * 64];
  __shared__ __align__(16) unsigned short Ps[4][16 * 64];

  // block remap: 4 consecutive bh per XCD; complementary qt pairing so each
  // CU's 4 resident blocks carry ~equal causal work.
  const int lin = blockIdx.y * gridDim.x + blockIdx.x;  // 0..1023
  const int xcd = lin & 7, idx = lin >> 3;              // idx 0..127
  const int bh = xcd * 4 + (idx >> 5);                  // 0..31
  const int s = idx & 31;
  const int qt = (s & 1) ? (31 - (s >> 1)) : (s >> 1);  // pair {i, 31-i}
  const int b = bh >> 4, h = bh & 15;
  const int q0 = qt * 64;

  const int w = threadIdx.x >> 6, lane = threadIdx.x & 63;
  const int lm = lane & 15, q4 = lane >> 4;
  const int len = lengths[b];
  const unsigned short* Qp = Q + (size_t)bh * S_ * HD_;
  const unsigned short* Kp = Kg + (size_t)bh * S_ * HD_;
  const unsigned short* Vp = Vt + (size_t)bh * HD_ * S_;

  // staging geometry: wave w stages tile rows [w*16, w*16+16), 8 rows/call.
  // lane -> (row offset r8, chunk c8); source chunk pre-swizzled: c8 ^ (row&7).
  const int r8 = lane >> 3, c8 = lane & 7;
  const int rs0 = w * 16 + r8, rs1 = rs0 + 8;           // (rs1&7) == (rs0&7)
  const int cs = (c8 ^ (rs0 & 7)) << 3;                 // chunk -> shorts
  const unsigned short* gK0 = Kp + (size_t)rs0 * HD_ + cs;
  const unsigned short* gK1 = Kp + (size_t)rs1 * HD_ + cs;
  const unsigned short* gV0 = Vp + (size_t)rs0 * S_ + cs;
  const unsigned short* gV1 = Vp + (size_t)rs1 * S_ + cs;
  unsigned short* dK0 = Ks + w * 16 * 64;
  unsigned short* dK1 = Ks + (w * 16 + 8) * 64;
  unsigned short* dV0 = Vs + w * 16 * 64;
  unsigned short* dV1 = Vs + (w * 16 + 8) * 64;

  const int qrow = q0 + w * 16 + lm;  // A-operand row for this lane
  short8 qf[2];
  qf[0] = *(const short8*)(Qp + (size_t)qrow * HD_ + q4 * 8);
  qf[1] = *(const short8*)(Qp + (size_t)qrow * HD_ + 32 + q4 * 8);

  const floatx4 z4 = {0.f, 0.f, 0.f, 0.f};
  floatx4 o[4];
#pragma unroll
  for (int dt = 0; dt < 4; dt++) o[dt] = z4;
  float m_i[4], l_i[4];
#pragma unroll
  for (int r = 0; r < 4; r++) { m_i[r] = -1e30f; l_i[r] = 0.0f; }

  unsigned short* ps = Ps[w];
  const int ktiles = min(qt + 1, (len + 63) >> 6);

  // prologue: stage tile 0 into buffer 0
  gl2lds16(gK0, dK0);
  gl2lds16(gK1, dK1);
  gl2lds16(gV0, dV0);
  gl2lds16(gV1, dV1);
  __syncthreads();

  int cur = 0;
  for (int kt = 0; kt < ktiles; kt++) {
    const int k0 = kt * 64;
    // issue next tile's staging into the other buffer (drains at the barrier)
    if (kt + 1 < ktiles) {
      const size_t koff = (size_t)(k0 + 64) * HD_;
      const int nb = (cur ^ 1) * 4096;
      gl2lds16(gK0 + koff, dK0 + nb);
      gl2lds16(gK1 + koff, dK1 + nb);
      gl2lds16(gV0 + (k0 + 64), dV0 + nb);
      gl2lds16(gV1 + (k0 + 64), dV1 + nb);
    }
    const unsigned short* kc = Ks + cur * 4096;
    const unsigned short* vc = Vs + cur * 4096;

    // S = Q K^T  (64 cols in 4 n-tiles); K frags from swizzled LDS.
    // First MFMA consumes z4 as C -> no per-tile acc zeroing.
    floatx4 sc[4];
#pragma unroll
    for (int nt = 0; nt < 4; nt++) {
      const int row = nt * 16 + lm, sw = row & 7;
      const unsigned short* kb = kc + row * 64;
      const short8 b0 = *(const short8*)(kb + ((q4 ^ sw) << 3));
      const short8 b1 = *(const short8*)(kb + (((q4 + 4) ^ sw) << 3));
      sc[nt] = __builtin_amdgcn_mfma_f32_16x16x32_bf16(qf[0], b0, z4, 0, 0, 0);
      sc[nt] = __builtin_amdgcn_mfma_f32_16x16x32_bf16(qf[1], b1, sc[nt], 0, 0, 0);
    }
    // mask only where it can trigger: diagonal tile or len-tail tile
    // (wave-uniform branch; interior tiles skip ~48 VALU ops/lane)
    if (kt == qt || k0 + 64 > len) {
#pragma unroll
      for (int nt = 0; nt < 4; nt++) {
        const int col = k0 + nt * 16 + lm;
#pragma unroll
        for (int r = 0; r < 4; r++) {
          const int row = q0 + w * 16 + q4 * 4 + r;
          if (col > row || col >= len) sc[nt][r] = -1e30f;
        }
      }
    }
    // online softmax, base-2 domain (scores already scaled by log2 e)
#pragma unroll
    for (int r = 0; r < 4; r++) {
      float mx = fmaxf(fmaxf(sc[0][r], sc[1][r]), fmaxf(sc[2][r], sc[3][r]));
#pragma unroll
      for (int off = 1; off < 16; off <<= 1) mx = fmaxf(mx, __shfl_xor(mx, off));
      const float mt = fmaxf(m_i[r], mx);
      const float al = __ocml_native_exp2_f32(m_i[r] - mt);
      float rs = 0.0f;
#pragma unroll
      for (int nt = 0; nt < 4; nt++) {
        const float pp = __ocml_native_exp2_f32(sc[nt][r] - mt);
        sc[nt][r] = pp;
        rs += pp;
      }
#pragma unroll
      for (int off = 1; off < 16; off <<= 1) rs += __shfl_xor(rs, off);
      l_i[r] = l_i[r] * al + rs;
      m_i[r] = mt;
#pragma unroll
      for (int dt = 0; dt < 4; dt++) o[dt][r] *= al;
    }
    // P: D-layout -> bf16 -> wave-private LDS strip, stride 64 + chunk-XOR
    // swizzle (phys chunk = logical chunk ^ (row&7)); wave-private + in-order
    // DS => no barrier needed.
#pragma unroll
    for (int nt = 0; nt < 4; nt++)
#pragma unroll
      for (int r = 0; r < 4; r++) {
        const int row = q4 * 4 + r;
        const int c = (((nt * 2 + (lm >> 3)) ^ (row & 7)) << 3) | (lm & 7);
        ps[row * 64 + c] = f2bf(sc[nt][r]);
      }
    // O += P V   (V^T rows are d; V frags from swizzled LDS)
#pragma unroll
    for (int ks = 0; ks < 2; ks++) {
      const short8 pf = *(const short8*)(
          ps + lm * 64 + ((((ks << 2) + q4) ^ (lm & 7)) << 3));
#pragma unroll
      for (int dt = 0; dt < 4; dt++) {
        const int row = dt * 16 + lm, sw = row & 7;
        const short8 vf = *(const short8*)(
            vc + row * 64 + ((((ks << 2) + q4) ^ sw) << 3));
        o[dt] = __builtin_amdgcn_mfma_f32_16x16x32_bf16(pf, vf, o[dt], 0, 0, 0);
      }
    }
    __syncthreads();  // drains next-tile staging; all waves done reading cur
    cur ^= 1;
  }
  // normalize + write attn (B,S,DM) bf16; col = h*64 + d
  float invl[4];
#pragma unroll
  for (int r = 0; r < 4; r++) invl[r] = 1.0f / l_i[r];
#pragma unroll
  for (int dt = 0; dt < 4; dt++)
#pragma unroll
    for (int r = 0; r < 4; r++) {
      const int row = q0 + w * 16 + q4 * 4 + r;
      const int col = h * HD_ + dt * 16 + lm;
      Oa[((size_t)b * S_ + row) * DM_ + col] = f2bf(o[dt][r] * invl[r]);
    }
}

// ---------------------------------------------------------------------------
// Out projection (bf16 MFMA): C[m][n] = sum_k A[m][k] * W[n][k], fp32 out.
// M=4096, N=1024, K=1024. Operands swapped so each thread holds 4 consecutive
// n at fixed m -> one float4 (16B) store per (nt,mt).
// ---------------------------------------------------------------------------
__global__ __launch_bounds__(256) void out_gemm(
    const unsigned short* __restrict__ A, const unsigned short* __restrict__ W,
    float* __restrict__ C) {
  __shared__ __align__(16) unsigned short As[128 * 32];
  __shared__ __align__(16) unsigned short Bs[128 * 32];
  const int m0 = blockIdx.y * 128, n0 = blockIdx.x * 128;
  const int w = threadIdx.x >> 6, lane = threadIdx.x & 63;
  const int lm = lane & 15, q4 = lane >> 4;
  const int srow = w * 32;
  const int r_in = lane >> 2, c_in = (lane & 3) * 8;
  const int wr = (w >> 1) * 64, wc = (w & 1) * 64;
  floatx4 acc[4][4];  // acc[nt][mt]: row <-> n, col <-> m
  const floatx4 z4 = {0.f, 0.f, 0.f, 0.f};
#pragma unroll
  for (int i = 0; i < 4; i++)
#pragma unroll
    for (int j = 0; j < 4; j++) acc[i][j] = z4;

  for (int k0 = 0; k0 < DM_; k0 += 32) {
    gl2lds16(A + (size_t)(m0 + srow + r_in) * DM_ + k0 + c_in, As + srow * 32);
    gl2lds16(A + (size_t)(m0 + srow + 16 + r_in) * DM_ + k0 + c_in,
             As + (srow + 16) * 32);
    gl2lds16(W + (size_t)(n0 + srow + r_in) * DM_ + k0 + c_in, Bs + srow * 32);
    gl2lds16(W + (size_t)(n0 + srow + 16 + r_in) * DM_ + k0 + c_in,
             Bs + (srow + 16) * 32);
    __syncthreads();
    short8 af[4], bf[4];
#pragma unroll
    for (int t = 0; t < 4; t++)
      af[t] = *(const short8*)(As + (wr + t * 16 + lm) * 32 + q4 * 8);
#pragma unroll
    for (int t = 0; t < 4; t++)
      bf[t] = *(const short8*)(Bs + (wc + t * 16 + lm) * 32 + q4 * 8);
#pragma unroll
    for (int i = 0; i < 4; i++)
#pragma unroll
      for (int j = 0; j < 4; j++)
        acc[i][j] =
            __builtin_amdgcn_mfma_f32_16x16x32_bf16(bf[i], af[j], acc[i][j],
                                                    0, 0, 0);
    __syncthreads();
  }
#pragma unroll
  for (int nt = 0; nt < 4; nt++) {
    const int nbase = n0 + wc + nt * 16 + q4 * 4;
#pragma unroll
    for (int mt = 0; mt < 4; mt++) {
      const int m = m0 + wr + mt * 16 + lm;
      *(floatx4*)(C + (size_t)m * DM_ + nbase) = acc[nt][mt];
    }
  }
}

}  // namespace

extern "C" void kernel_launch(void* const* d_in, const int* in_sizes, int n_in,
                              void* d_out, int out_size, void* d_ws, size_t ws_size,
                              hipStream_t stream) {
  const float* hidden = (const float*)d_in[0];          // (2,2048,1024) f32
  const float* w_qkv = (const float*)d_in[1];           // (3072,1024) f32
  const float* w_out = (const float*)d_in[2];           // (1024,1024) f32
  const unsigned char* amask = (const unsigned char*)d_in[3];  // (2,2048) bool
  const int* pos_xyz = (const int*)d_in[5];             // (2,2048,3) i32
  float* out = (float*)d_out;                           // (2,2048,1024) f32

  constexpr size_t NHID = (size_t)B_ * S_ * DM_;        // 4,194,304
  constexpr size_t NWQ = (size_t)3 * DM_ * DM_;         // 3,145,728
  constexpr size_t NWO = (size_t)DM_ * DM_;             // 1,048,576
  constexpr size_t NQKV = (size_t)B_ * NH_ * S_ * HD_;  // 4,194,304

  unsigned short* hb = (unsigned short*)d_ws;
  unsigned short* wqb = hb + NHID;
  unsigned short* wob = wqb + NWQ;
  unsigned short* Qb = wob + NWO;
  unsigned short* Kb = Qb + NQKV;
  unsigned short* Vtb = Kb + NQKV;
  unsigned short* attn = Vtb + NQKV;
  int* lens = (int*)(attn + NQKV);

  cvt_bf16<<<dim3(NHID / 8 / 256), dim3(256), 0, stream>>>(hidden, hb,
                                                           (int)(NHID / 8));
  cvt_bf16<<<dim3(NWQ / 8 / 256), dim3(256), 0, stream>>>(w_qkv, wqb,
                                                          (int)(NWQ / 8));
  cvt_bf16<<<dim3(NWO / 8 / 256), dim3(256), 0, stream>>>(w_out, wob,
                                                          (int)(NWO / 8));
  lengths_kernel<<<dim3(B_), dim3(256), 0, stream>>>(amask, lens);
  qkv_gemm<<<dim3(3 * DM_ / 128, B_ * S_ / 128), dim3(256), 0, stream>>>(
      hb, wqb, pos_xyz, Qb, Kb, Vtb);
  flash_mfma<<<dim3(S_ / 64, B_ * NH_), dim3(256), 0, stream>>>(
      Qb, Kb, Vtb, lens, attn);
  out_gemm<<<dim3(DM_ / 128, B_ * S_ / 128), dim3(256), 0, stream>>>(
      attn, wob, out);
}

// Round 6
// 246.059 us; speedup vs baseline: 1.1725x; 1.1725x over previous
//
#include <hip/hip_runtime.h>
#include <math.h>

extern "C" __device__ float __ocml_native_exp2_f32(float);

namespace {

typedef __attribute__((ext_vector_type(8))) short short8;   // 8 bf16 = 4 VGPRs
typedef __attribute__((ext_vector_type(4))) short short4b;  // 4 bf16 = 8B store
typedef __attribute__((ext_vector_type(4))) float floatx4;  // MFMA C/D frag

constexpr int B_ = 2;
constexpr int S_ = 2048;
constexpr int DM_ = 1024;
constexpr int NH_ = 16;
constexpr int HD_ = 64;

// fp32 -> bf16 round-to-nearest-even
__device__ inline unsigned short f2bf(float f) {
  unsigned u = __builtin_bit_cast(unsigned, f);
  u += 0x7fffu + ((u >> 16) & 1u);
  return (unsigned short)(u >> 16);
}

// DPP row-rotate (within 16-lane rows) — reduction butterflies without LDS.
// ctrl = 0x120 | N  (row_ror:N). All lanes active at call sites.
template <int CTRL>
__device__ inline float dpp_ror(float x) {
  const int r = __builtin_amdgcn_update_dpp(
      0, __builtin_bit_cast(int, x), CTRL, 0xF, 0xF, false);
  return __builtin_bit_cast(float, r);
}

// async global->LDS, 16B per lane; lds dest must be wave-uniform (lane i lands
// at lds + i*16).
__device__ inline void gl2lds16(const unsigned short* g, unsigned short* l) {
  __builtin_amdgcn_global_load_lds(
      (const __attribute__((address_space(1))) unsigned int*)g,
      (__attribute__((address_space(3))) unsigned int*)l, 16, 0, 0);
}

// ---------------------------------------------------------------------------
__global__ void cvt_bf16(const float* __restrict__ in,
                         unsigned short* __restrict__ out, int n8) {
  const int i = blockIdx.x * blockDim.x + threadIdx.x;
  if (i >= n8) return;
  const float4 a = ((const float4*)in)[i * 2];
  const float4 b = ((const float4*)in)[i * 2 + 1];
  short8 v;
  v[0] = (short)f2bf(a.x); v[1] = (short)f2bf(a.y);
  v[2] = (short)f2bf(a.z); v[3] = (short)f2bf(a.w);
  v[4] = (short)f2bf(b.x); v[5] = (short)f2bf(b.y);
  v[6] = (short)f2bf(b.z); v[7] = (short)f2bf(b.w);
  ((short8*)out)[i] = v;
}

// ---------------------------------------------------------------------------
__global__ void lengths_kernel(const unsigned char* __restrict__ mask,
                               int* __restrict__ lengths) {
  const int es1 = (mask[1] != 0);  // byte-1 nonzero => 1-byte bool storage
  const int b = blockIdx.x;
  __shared__ int cnt;
  if (threadIdx.x == 0) cnt = 0;
  __syncthreads();
  int local = 0;
  for (int s = threadIdx.x; s < S_; s += blockDim.x) {
    bool nz;
    if (es1) nz = mask[b * S_ + s] != 0;
    else     nz = ((const unsigned int*)mask)[b * S_ + s] != 0;
    local += nz ? 1 : 0;
  }
  atomicAdd(&cnt, local);
  __syncthreads();
  if (threadIdx.x == 0) lengths[b] = cnt;
}

// ---------------------------------------------------------------------------
// QKV GEMM (bf16 MFMA): C[m][n] = sum_k A[m][k] * W[n][k]
// M=4096, N=3072, K=1024. 128x128 tile, BK=32, 4 waves each 64x64.
// Coalesced epilogues: Q/K via swapped MFMA operands (RoPE in-register,
// 8B packed stores), V via packed 8B stores into V^T.
// NOTE: q is pre-scaled by 1/sqrt(64) * log2(e) so flash softmax can run in
// base-2 (v_exp_f32 directly, no per-element multiply).
// ---------------------------------------------------------------------------
__global__ __launch_bounds__(256) void qkv_gemm(
    const unsigned short* __restrict__ A, const unsigned short* __restrict__ W,
    const int* __restrict__ pos_xyz,
    unsigned short* __restrict__ Qb, unsigned short* __restrict__ Kb,
    unsigned short* __restrict__ Vtb) {
  __shared__ __align__(16) unsigned short As[128 * 32];
  __shared__ __align__(16) unsigned short Bs[128 * 32];
  const int m0 = blockIdx.y * 128, n0 = blockIdx.x * 128;
  const int w = threadIdx.x >> 6, lane = threadIdx.x & 63;
  const int lm = lane & 15, q4 = lane >> 4;
  const int srow = w * 32;                  // this wave's staging rows
  const int r_in = lane >> 2, c_in = (lane & 3) * 8;
  const int wr = (w >> 1) * 64, wc = (w & 1) * 64;
  const int which = n0 >> 10;               // 0=Q 1=K 2=V (block-uniform)
  floatx4 acc[4][4];
  const floatx4 z4 = {0.f, 0.f, 0.f, 0.f};
#pragma unroll
  for (int i = 0; i < 4; i++)
#pragma unroll
    for (int j = 0; j < 4; j++) acc[i][j] = z4;

  for (int k0 = 0; k0 < DM_; k0 += 32) {
    gl2lds16(A + (size_t)(m0 + srow + r_in) * DM_ + k0 + c_in, As + srow * 32);
    gl2lds16(A + (size_t)(m0 + srow + 16 + r_in) * DM_ + k0 + c_in,
             As + (srow + 16) * 32);
    gl2lds16(W + (size_t)(n0 + srow + r_in) * DM_ + k0 + c_in, Bs + srow * 32);
    gl2lds16(W + (size_t)(n0 + srow + 16 + r_in) * DM_ + k0 + c_in,
             Bs + (srow + 16) * 32);
    __syncthreads();
    short8 af[4], bf[4];
#pragma unroll
    for (int t = 0; t < 4; t++)
      af[t] = *(const short8*)(As + (wr + t * 16 + lm) * 32 + q4 * 8);
#pragma unroll
    for (int t = 0; t < 4; t++)
      bf[t] = *(const short8*)(Bs + (wc + t * 16 + lm) * 32 + q4 * 8);
    if (which == 2) {
      // acc[mt][nt]: row <-> m(si), col <-> n(d)
#pragma unroll
      for (int i = 0; i < 4; i++)
#pragma unroll
        for (int j = 0; j < 4; j++)
          acc[i][j] = __builtin_amdgcn_mfma_f32_16x16x32_bf16(af[i], bf[j],
                                                              acc[i][j], 0, 0, 0);
    } else {
      // swapped: acc[nt][mt]: row <-> n(d), col <-> m(si)
#pragma unroll
      for (int i = 0; i < 4; i++)
#pragma unroll
        for (int j = 0; j < 4; j++)
          acc[i][j] = __builtin_amdgcn_mfma_f32_16x16x32_bf16(bf[i], af[j],
                                                              acc[i][j], 0, 0, 0);
    }
    __syncthreads();
  }

  const int h = ((n0 + wc) & 1023) >> 6;  // wave-uniform head
  if (which == 2) {
#pragma unroll
    for (int nt = 0; nt < 4; nt++) {
      const int d = nt * 16 + lm;
#pragma unroll
      for (int mt = 0; mt < 4; mt++) {
        const int m = m0 + wr + mt * 16 + q4 * 4;
        const int bi = m >> 11, si = m & (S_ - 1);
        short4b pk;
#pragma unroll
        for (int r = 0; r < 4; r++) pk[r] = (short)f2bf(acc[mt][nt][r]);
        *(short4b*)(Vtb + ((size_t)(bi * NH_ + h) * HD_ + d) * S_ + si) = pk;
      }
    }
  } else {
    unsigned short* Dst = (which == 0) ? Qb : Kb;
    // q pre-scaled by 1/8 * log2(e) for base-2 flash softmax
    const float osc = (which == 0) ? 0.125f * 1.44269504088896f : 1.0f;
#pragma unroll
    for (int nt = 0; nt < 4; nt++) {
      const int dbase = nt * 16 + q4 * 4;  // even; both RoPE pairs in-register
      const int p0 = dbase >> 1;           // even -> p0,p0+1 share an axis
      int axis, j0, dseg;
      if (p0 < 10)      { axis = 0; j0 = p0;      dseg = 20; }
      else if (p0 < 20) { axis = 1; j0 = p0 - 10; dseg = 20; }
      else              { axis = 2; j0 = p0 - 20; dseg = 24; }
      // 10000^(-2j/dseg) = exp(-2j/dseg * ln 1e4)
      const float invf0 =
          __expf(-(2.0f * (float)j0 / (float)dseg) * 9.210340371976184f);
      const float invf1 =
          __expf(-(2.0f * (float)(j0 + 1) / (float)dseg) * 9.210340371976184f);
#pragma unroll
      for (int mt = 0; mt < 4; mt++) {
        const int m = m0 + wr + mt * 16 + lm;
        const int bi = m >> 11, si = m & (S_ - 1);
        const int pos = pos_xyz[((size_t)bi * S_ + si) * 3 + axis];
        short4b pk;
#pragma unroll
        for (int u = 0; u < 2; u++) {
          const float ve = acc[nt][mt][2 * u], vo = acc[nt][mt][2 * u + 1];
          float sn, cs;
          sincosf((float)pos * (u ? invf1 : invf0), &sn, &cs);
          pk[2 * u]     = (short)f2bf(fmaf(ve, cs, -vo * sn) * osc);
          pk[2 * u + 1] = (short)f2bf(fmaf(vo, cs, ve * sn) * osc);
        }
        *(short4b*)(Dst + ((size_t)(bi * NH_ + h) * S_ + si) * HD_ + dbase) = pk;
      }
    }
  }
}

// ---------------------------------------------------------------------------
// Flash attention on MFMA. Block = (64 q-rows) x (b,h); 4 waves, each owns a
// 16-row q strip. K/V double-buffered in XOR-swizzled LDS via global_load_lds
// (prefetch at top of iter, drain at end-of-iter barrier). Softmax in base-2.
// Masking only on diagonal/len-tail tiles. Ps swizzled (stride 64) -> LDS =
// exactly 40960 B -> 4 blocks/CU, whole grid co-resident.
//
// Work balance (ALL blocks resident => makespan = worst CU, no refill):
// qt = (s&1) ? 31-p(c) : p(c), p(c) = (c&1) ? 31-(c>>1) : (c>>1).
// Balanced under BOTH plausible within-XCD block->CU groupings:
//   stride-32 {c fixed, s=0..3}: {p,31-p,p,31-p} = 66 tiles;
//   contiguous-4 {s fixed, 4c..4c+3}: {2c,31-2c,2c+1,30-2c} = 66 tiles.
// Row-softmax reductions use DPP row_ror butterflies (VALU) instead of
// __shfl_xor (ds_swizzle) -> 32 fewer LDS-pipe ops per tile per wave.
// ---------------------------------------------------------------------------
__global__ __launch_bounds__(256) void flash_mfma(
    const unsigned short* __restrict__ Q, const unsigned short* __restrict__ Kg,
    const unsigned short* __restrict__ Vt, const int* __restrict__ lengths,
    unsigned short* __restrict__ Oa) {
  __shared__ __align__(16) unsigned short Ks[2 * 64 * 64];
  __shared__ __align__(16) unsigned short Vs[2 * 64 * 64];
  __shared__ __align__(16) unsigned short Ps[4][16 * 64];

  const int lin = blockIdx.y * gridDim.x + blockIdx.x;  // 0..1023
  const int xcd = lin & 7, k = lin >> 3;                // k 0..127 within XCD
  const int s = k >> 5, c = k & 31;
  const int pc = (c & 1) ? 31 - (c >> 1) : (c >> 1);    // pair permutation
  const int qt = (s & 1) ? 31 - pc : pc;
  const int bh = xcd * 4 + s;                           // 4 bh per XCD (L2)
  const int b = bh >> 4, h = bh & 15;
  const int q0 = qt * 64;

  const int w = threadIdx.x >> 6, lane = threadIdx.x & 63;
  const int lm = lane & 15, q4 = lane >> 4;
  const int len = lengths[b];
  const unsigned short* Qp = Q + (size_t)bh * S_ * HD_;
  const unsigned short* Kp = Kg + (size_t)bh * S_ * HD_;
  const unsigned short* Vp = Vt + (size_t)bh * HD_ * S_;

  // staging geometry: wave w stages tile rows [w*16, w*16+16), 8 rows/call.
  // lane -> (row offset r8, chunk c8); source chunk pre-swizzled: c8 ^ (row&7).
  const int r8 = lane >> 3, c8 = lane & 7;
  const int rs0 = w * 16 + r8, rs1 = rs0 + 8;           // (rs1&7) == (rs0&7)
  const int cs = (c8 ^ (rs0 & 7)) << 3;                 // chunk -> shorts
  const unsigned short* gK0 = Kp + (size_t)rs0 * HD_ + cs;
  const unsigned short* gK1 = Kp + (size_t)rs1 * HD_ + cs;
  const unsigned short* gV0 = Vp + (size_t)rs0 * S_ + cs;
  const unsigned short* gV1 = Vp + (size_t)rs1 * S_ + cs;
  unsigned short* dK0 = Ks + w * 16 * 64;
  unsigned short* dK1 = Ks + (w * 16 + 8) * 64;
  unsigned short* dV0 = Vs + w * 16 * 64;
  unsigned short* dV1 = Vs + (w * 16 + 8) * 64;

  const int qrow = q0 + w * 16 + lm;  // A-operand row for this lane
  short8 qf[2];
  qf[0] = *(const short8*)(Qp + (size_t)qrow * HD_ + q4 * 8);
  qf[1] = *(const short8*)(Qp + (size_t)qrow * HD_ + 32 + q4 * 8);

  const floatx4 z4 = {0.f, 0.f, 0.f, 0.f};
  floatx4 o[4];
#pragma unroll
  for (int dt = 0; dt < 4; dt++) o[dt] = z4;
  float m_i[4], l_i[4];
#pragma unroll
  for (int r = 0; r < 4; r++) { m_i[r] = -1e30f; l_i[r] = 0.0f; }

  unsigned short* ps = Ps[w];
  const int ktiles = min(qt + 1, (len + 63) >> 6);

  // prologue: stage tile 0 into buffer 0
  gl2lds16(gK0, dK0);
  gl2lds16(gK1, dK1);
  gl2lds16(gV0, dV0);
  gl2lds16(gV1, dV1);
  __syncthreads();

  int cur = 0;
  for (int kt = 0; kt < ktiles; kt++) {
    const int k0 = kt * 64;
    // issue next tile's staging into the other buffer (drains at the barrier)
    if (kt + 1 < ktiles) {
      const size_t koff = (size_t)(k0 + 64) * HD_;
      const int nb = (cur ^ 1) * 4096;
      gl2lds16(gK0 + koff, dK0 + nb);
      gl2lds16(gK1 + koff, dK1 + nb);
      gl2lds16(gV0 + (k0 + 64), dV0 + nb);
      gl2lds16(gV1 + (k0 + 64), dV1 + nb);
    }
    const unsigned short* kc = Ks + cur * 4096;
    const unsigned short* vc = Vs + cur * 4096;

    // S = Q K^T  (64 cols in 4 n-tiles); K frags from swizzled LDS.
    floatx4 sc[4];
#pragma unroll
    for (int nt = 0; nt < 4; nt++) {
      const int row = nt * 16 + lm, sw = row & 7;
      const unsigned short* kb = kc + row * 64;
      const short8 b0 = *(const short8*)(kb + ((q4 ^ sw) << 3));
      const short8 b1 = *(const short8*)(kb + (((q4 + 4) ^ sw) << 3));
      sc[nt] = __builtin_amdgcn_mfma_f32_16x16x32_bf16(qf[0], b0, z4, 0, 0, 0);
      sc[nt] = __builtin_amdgcn_mfma_f32_16x16x32_bf16(qf[1], b1, sc[nt], 0, 0, 0);
    }
    // mask only where it can trigger: diagonal tile or len-tail tile
    if (kt == qt || k0 + 64 > len) {
#pragma unroll
      for (int nt = 0; nt < 4; nt++) {
        const int col = k0 + nt * 16 + lm;
#pragma unroll
        for (int r = 0; r < 4; r++) {
          const int row = q0 + w * 16 + q4 * 4 + r;
          if (col > row || col >= len) sc[nt][r] = -1e30f;
        }
      }
    }
    // online softmax, base-2 domain; 16-lane reductions via DPP row_ror
#pragma unroll
    for (int r = 0; r < 4; r++) {
      float mx = fmaxf(fmaxf(sc[0][r], sc[1][r]), fmaxf(sc[2][r], sc[3][r]));
      mx = fmaxf(mx, dpp_ror<0x121>(mx));
      mx = fmaxf(mx, dpp_ror<0x122>(mx));
      mx = fmaxf(mx, dpp_ror<0x124>(mx));
      mx = fmaxf(mx, dpp_ror<0x128>(mx));
      const float mt = fmaxf(m_i[r], mx);
      const float al = __ocml_native_exp2_f32(m_i[r] - mt);
      float rs = 0.0f;
#pragma unroll
      for (int nt = 0; nt < 4; nt++) {
        const float pp = __ocml_native_exp2_f32(sc[nt][r] - mt);
        sc[nt][r] = pp;
        rs += pp;
      }
      rs += dpp_ror<0x121>(rs);
      rs += dpp_ror<0x122>(rs);
      rs += dpp_ror<0x124>(rs);
      rs += dpp_ror<0x128>(rs);
      l_i[r] = l_i[r] * al + rs;
      m_i[r] = mt;
#pragma unroll
      for (int dt = 0; dt < 4; dt++) o[dt][r] *= al;
    }
    // P: D-layout -> bf16 -> wave-private LDS strip, stride 64 + chunk-XOR
    // swizzle; wave-private + in-order DS => no barrier needed.
#pragma unroll
    for (int nt = 0; nt < 4; nt++)
#pragma unroll
      for (int r = 0; r < 4; r++) {
        const int row = q4 * 4 + r;
        const int cc = (((nt * 2 + (lm >> 3)) ^ (row & 7)) << 3) | (lm & 7);
        ps[row * 64 + cc] = f2bf(sc[nt][r]);
      }
    // O += P V   (V^T rows are d; V frags from swizzled LDS)
#pragma unroll
    for (int ks = 0; ks < 2; ks++) {
      const short8 pf = *(const short8*)(
          ps + lm * 64 + ((((ks << 2) + q4) ^ (lm & 7)) << 3));
#pragma unroll
      for (int dt = 0; dt < 4; dt++) {
        const int row = dt * 16 + lm, sw = row & 7;
        const short8 vf = *(const short8*)(
            vc + row * 64 + ((((ks << 2) + q4) ^ sw) << 3));
        o[dt] = __builtin_amdgcn_mfma_f32_16x16x32_bf16(pf, vf, o[dt], 0, 0, 0);
      }
    }
    __syncthreads();  // drains next-tile staging; all waves done reading cur
    cur ^= 1;
  }
  // normalize + write attn (B,S,DM) bf16; col = h*64 + d
  float invl[4];
#pragma unroll
  for (int r = 0; r < 4; r++) invl[r] = 1.0f / l_i[r];
#pragma unroll
  for (int dt = 0; dt < 4; dt++)
#pragma unroll
    for (int r = 0; r < 4; r++) {
      const int row = q0 + w * 16 + q4 * 4 + r;
      const int col = h * HD_ + dt * 16 + lm;
      Oa[((size_t)b * S_ + row) * DM_ + col] = f2bf(o[dt][r] * invl[r]);
    }
}

// ---------------------------------------------------------------------------
// Out projection (bf16 MFMA): C[m][n] = sum_k A[m][k] * W[n][k], fp32 out.
// M=4096, N=1024, K=1024. Operands swapped so each thread holds 4 consecutive
// n at fixed m -> one float4 (16B) store per (nt,mt).
// ---------------------------------------------------------------------------
__global__ __launch_bounds__(256) void out_gemm(
    const unsigned short* __restrict__ A, const unsigned short* __restrict__ W,
    float* __restrict__ C) {
  __shared__ __align__(16) unsigned short As[128 * 32];
  __shared__ __align__(16) unsigned short Bs[128 * 32];
  const int m0 = blockIdx.y * 128, n0 = blockIdx.x * 128;
  const int w = threadIdx.x >> 6, lane = threadIdx.x & 63;
  const int lm = lane & 15, q4 = lane >> 4;
  const int srow = w * 32;
  const int r_in = lane >> 2, c_in = (lane & 3) * 8;
  const int wr = (w >> 1) * 64, wc = (w & 1) * 64;
  floatx4 acc[4][4];  // acc[nt][mt]: row <-> n, col <-> m
  const floatx4 z4 = {0.f, 0.f, 0.f, 0.f};
#pragma unroll
  for (int i = 0; i < 4; i++)
#pragma unroll
    for (int j = 0; j < 4; j++) acc[i][j] = z4;

  for (int k0 = 0; k0 < DM_; k0 += 32) {
    gl2lds16(A + (size_t)(m0 + srow + r_in) * DM_ + k0 + c_in, As + srow * 32);
    gl2lds16(A + (size_t)(m0 + srow + 16 + r_in) * DM_ + k0 + c_in,
             As + (srow + 16) * 32);
    gl2lds16(W + (size_t)(n0 + srow + r_in) * DM_ + k0 + c_in, Bs + srow * 32);
    gl2lds16(W + (size_t)(n0 + srow + 16 + r_in) * DM_ + k0 + c_in,
             Bs + (srow + 16) * 32);
    __syncthreads();
    short8 af[4], bf[4];
#pragma unroll
    for (int t = 0; t < 4; t++)
      af[t] = *(const short8*)(As + (wr + t * 16 + lm) * 32 + q4 * 8);
#pragma unroll
    for (int t = 0; t < 4; t++)
      bf[t] = *(const short8*)(Bs + (wc + t * 16 + lm) * 32 + q4 * 8);
#pragma unroll
    for (int i = 0; i < 4; i++)
#pragma unroll
      for (int j = 0; j < 4; j++)
        acc[i][j] =
            __builtin_amdgcn_mfma_f32_16x16x32_bf16(bf[i], af[j], acc[i][j],
                                                    0, 0, 0);
    __syncthreads();
  }
#pragma unroll
  for (int nt = 0; nt < 4; nt++) {
    const int nbase = n0 + wc + nt * 16 + q4 * 4;
#pragma unroll
    for (int mt = 0; mt < 4; mt++) {
      const int m = m0 + wr + mt * 16 + lm;
      *(floatx4*)(C + (size_t)m * DM_ + nbase) = acc[nt][mt];
    }
  }
}

}  // namespace

extern "C" void kernel_launch(void* const* d_in, const int* in_sizes, int n_in,
                              void* d_out, int out_size, void* d_ws, size_t ws_size,
                              hipStream_t stream) {
  const float* hidden = (const float*)d_in[0];          // (2,2048,1024) f32
  const float* w_qkv = (const float*)d_in[1];           // (3072,1024) f32
  const float* w_out = (const float*)d_in[2];           // (1024,1024) f32
  const unsigned char* amask = (const unsigned char*)d_in[3];  // (2,2048) bool
  const int* pos_xyz = (const int*)d_in[5];             // (2,2048,3) i32
  float* out = (float*)d_out;                           // (2,2048,1024) f32

  constexpr size_t NHID = (size_t)B_ * S_ * DM_;        // 4,194,304
  constexpr size_t NWQ = (size_t)3 * DM_ * DM_;         // 3,145,728
  constexpr size_t NWO = (size_t)DM_ * DM_;             // 1,048,576
  constexpr size_t NQKV = (size_t)B_ * NH_ * S_ * HD_;  // 4,194,304

  unsigned short* hb = (unsigned short*)d_ws;
  unsigned short* wqb = hb + NHID;
  unsigned short* wob = wqb + NWQ;
  unsigned short* Qb = wob + NWO;
  unsigned short* Kb = Qb + NQKV;
  unsigned short* Vtb = Kb + NQKV;
  unsigned short* attn = Vtb + NQKV;
  int* lens = (int*)(attn + NQKV);

  cvt_bf16<<<dim3(NHID / 8 / 256), dim3(256), 0, stream>>>(hidden, hb,
                                                           (int)(NHID / 8));
  cvt_bf16<<<dim3(NWQ / 8 / 256), dim3(256), 0, stream>>>(w_qkv, wqb,
                                                          (int)(NWQ / 8));
  cvt_bf16<<<dim3(NWO / 8 / 256), dim3(256), 0, stream>>>(w_out, wob,
                                                          (int)(NWO / 8));
  lengths_kernel<<<dim3(B_), dim3(256), 0, stream>>>(amask, lens);
  qkv_gemm<<<dim3(3 * DM_ / 128, B_ * S_ / 128), dim3(256), 0, stream>>>(
      hb, wqb, pos_xyz, Qb, Kb, Vtb);
  flash_mfma<<<dim3(S_ / 64, B_ * NH_), dim3(256), 0, stream>>>(
      Qb, Kb, Vtb, lens, attn);
  out_gemm<<<dim3(DM_ / 128, B_ * S_ / 128), dim3(256), 0, stream>>>(
      attn, wob, out);
}

// Round 7
// 240.466 us; speedup vs baseline: 1.1997x; 1.0233x over previous
//
#include <hip/hip_runtime.h>
#include <math.h>

extern "C" __device__ float __ocml_native_exp2_f32(float);

namespace {

typedef __attribute__((ext_vector_type(8))) short short8;   // 8 bf16 = 4 VGPRs
typedef __attribute__((ext_vector_type(4))) short short4b;  // 4 bf16 = 8B store
typedef __attribute__((ext_vector_type(4))) float floatx4;  // MFMA C/D frag

constexpr int B_ = 2;
constexpr int S_ = 2048;
constexpr int DM_ = 1024;
constexpr int NH_ = 16;
constexpr int HD_ = 64;

// fp32 -> bf16 round-to-nearest-even
__device__ inline unsigned short f2bf(float f) {
  unsigned u = __builtin_bit_cast(unsigned, f);
  u += 0x7fffu + ((u >> 16) & 1u);
  return (unsigned short)(u >> 16);
}

// DPP row-rotate (within 16-lane rows) — reduction butterflies without LDS.
// ctrl = 0x120 | N  (row_ror:N). All lanes active at call sites.
template <int CTRL>
__device__ inline float dpp_ror(float x) {
  const int r = __builtin_amdgcn_update_dpp(
      0, __builtin_bit_cast(int, x), CTRL, 0xF, 0xF, false);
  return __builtin_bit_cast(float, r);
}

// async global->LDS, 16B per lane; lds dest must be wave-uniform (lane i lands
// at lds + i*16).
__device__ inline void gl2lds16(const unsigned short* g, unsigned short* l) {
  __builtin_amdgcn_global_load_lds(
      (const __attribute__((address_space(1))) unsigned int*)g,
      (__attribute__((address_space(3))) unsigned int*)l, 16, 0, 0);
}

// ---------------------------------------------------------------------------
// Fused prep: one launch does all three f32->bf16 conversions (dsts are
// contiguous in workspace: hb | wqb | wob) + the 2 length reductions.
// Ranges are block-aligned (2048 / 1536 / 512 blocks) -> no divergence.
// ---------------------------------------------------------------------------
__global__ __launch_bounds__(256) void prep(
    const float* __restrict__ hidden, const float* __restrict__ wqkv,
    const float* __restrict__ wout, const unsigned char* __restrict__ mask,
    unsigned short* __restrict__ hb, int* __restrict__ lengths) {
  const int bid = blockIdx.x;
  if (bid < 4096) {
    const int i = bid * 256 + threadIdx.x;  // short8 index into combined dst
    const float* src;
    int off;
    if (i < 524288)              { src = hidden; off = 0; }
    else if (i < 524288 + 393216){ src = wqkv;   off = 524288; }
    else                         { src = wout;   off = 524288 + 393216; }
    const size_t j = (size_t)(i - off);
    const float4 a = ((const float4*)src)[j * 2];
    const float4 b = ((const float4*)src)[j * 2 + 1];
    short8 v;
    v[0] = (short)f2bf(a.x); v[1] = (short)f2bf(a.y);
    v[2] = (short)f2bf(a.z); v[3] = (short)f2bf(a.w);
    v[4] = (short)f2bf(b.x); v[5] = (short)f2bf(b.y);
    v[6] = (short)f2bf(b.z); v[7] = (short)f2bf(b.w);
    ((short8*)hb)[i] = v;
  } else {
    const int b = bid - 4096;
    const int es1 = (mask[1] != 0);  // byte-1 nonzero => 1-byte bool storage
    __shared__ int cnt;
    if (threadIdx.x == 0) cnt = 0;
    __syncthreads();
    int local = 0;
    for (int s = threadIdx.x; s < S_; s += blockDim.x) {
      bool nz;
      if (es1) nz = mask[b * S_ + s] != 0;
      else     nz = ((const unsigned int*)mask)[b * S_ + s] != 0;
      local += nz ? 1 : 0;
    }
    atomicAdd(&cnt, local);
    __syncthreads();
    if (threadIdx.x == 0) lengths[b] = cnt;
  }
}

// ---------------------------------------------------------------------------
// QKV GEMM (bf16 MFMA): C[m][n] = sum_k A[m][k] * W[n][k]
// M=4096, N=3072, K=1024. 128x128 tile, BK=32, 4 waves each 64x64.
// Coalesced epilogues: Q/K via swapped MFMA operands (RoPE in-register,
// 8B packed stores), V via packed 8B stores into V^T.
// NOTE: q is pre-scaled by 1/sqrt(64) * log2(e) so flash softmax can run in
// base-2 (v_exp_f32 directly, no per-element multiply).
// ---------------------------------------------------------------------------
__global__ __launch_bounds__(256) void qkv_gemm(
    const unsigned short* __restrict__ A, const unsigned short* __restrict__ W,
    const int* __restrict__ pos_xyz,
    unsigned short* __restrict__ Qb, unsigned short* __restrict__ Kb,
    unsigned short* __restrict__ Vtb) {
  __shared__ __align__(16) unsigned short As[128 * 32];
  __shared__ __align__(16) unsigned short Bs[128 * 32];
  const int m0 = blockIdx.y * 128, n0 = blockIdx.x * 128;
  const int w = threadIdx.x >> 6, lane = threadIdx.x & 63;
  const int lm = lane & 15, q4 = lane >> 4;
  const int srow = w * 32;                  // this wave's staging rows
  const int r_in = lane >> 2, c_in = (lane & 3) * 8;
  const int wr = (w >> 1) * 64, wc = (w & 1) * 64;
  const int which = n0 >> 10;               // 0=Q 1=K 2=V (block-uniform)
  floatx4 acc[4][4];
  const floatx4 z4 = {0.f, 0.f, 0.f, 0.f};
#pragma unroll
  for (int i = 0; i < 4; i++)
#pragma unroll
    for (int j = 0; j < 4; j++) acc[i][j] = z4;

  for (int k0 = 0; k0 < DM_; k0 += 32) {
    gl2lds16(A + (size_t)(m0 + srow + r_in) * DM_ + k0 + c_in, As + srow * 32);
    gl2lds16(A + (size_t)(m0 + srow + 16 + r_in) * DM_ + k0 + c_in,
             As + (srow + 16) * 32);
    gl2lds16(W + (size_t)(n0 + srow + r_in) * DM_ + k0 + c_in, Bs + srow * 32);
    gl2lds16(W + (size_t)(n0 + srow + 16 + r_in) * DM_ + k0 + c_in,
             Bs + (srow + 16) * 32);
    __syncthreads();
    short8 af[4], bf[4];
#pragma unroll
    for (int t = 0; t < 4; t++)
      af[t] = *(const short8*)(As + (wr + t * 16 + lm) * 32 + q4 * 8);
#pragma unroll
    for (int t = 0; t < 4; t++)
      bf[t] = *(const short8*)(Bs + (wc + t * 16 + lm) * 32 + q4 * 8);
    if (which == 2) {
      // acc[mt][nt]: row <-> m(si), col <-> n(d)
#pragma unroll
      for (int i = 0; i < 4; i++)
#pragma unroll
        for (int j = 0; j < 4; j++)
          acc[i][j] = __builtin_amdgcn_mfma_f32_16x16x32_bf16(af[i], bf[j],
                                                              acc[i][j], 0, 0, 0);
    } else {
      // swapped: acc[nt][mt]: row <-> n(d), col <-> m(si)
#pragma unroll
      for (int i = 0; i < 4; i++)
#pragma unroll
        for (int j = 0; j < 4; j++)
          acc[i][j] = __builtin_amdgcn_mfma_f32_16x16x32_bf16(bf[i], af[j],
                                                              acc[i][j], 0, 0, 0);
    }
    __syncthreads();
  }

  const int h = ((n0 + wc) & 1023) >> 6;  // wave-uniform head
  if (which == 2) {
#pragma unroll
    for (int nt = 0; nt < 4; nt++) {
      const int d = nt * 16 + lm;
#pragma unroll
      for (int mt = 0; mt < 4; mt++) {
        const int m = m0 + wr + mt * 16 + q4 * 4;
        const int bi = m >> 11, si = m & (S_ - 1);
        short4b pk;
#pragma unroll
        for (int r = 0; r < 4; r++) pk[r] = (short)f2bf(acc[mt][nt][r]);
        *(short4b*)(Vtb + ((size_t)(bi * NH_ + h) * HD_ + d) * S_ + si) = pk;
      }
    }
  } else {
    unsigned short* Dst = (which == 0) ? Qb : Kb;
    // q pre-scaled by 1/8 * log2(e) for base-2 flash softmax
    const float osc = (which == 0) ? 0.125f * 1.44269504088896f : 1.0f;
#pragma unroll
    for (int nt = 0; nt < 4; nt++) {
      const int dbase = nt * 16 + q4 * 4;  // even; both RoPE pairs in-register
      const int p0 = dbase >> 1;           // even -> p0,p0+1 share an axis
      int axis, j0, dseg;
      if (p0 < 10)      { axis = 0; j0 = p0;      dseg = 20; }
      else if (p0 < 20) { axis = 1; j0 = p0 - 10; dseg = 20; }
      else              { axis = 2; j0 = p0 - 20; dseg = 24; }
      // 10000^(-2j/dseg) = exp(-2j/dseg * ln 1e4)
      const float invf0 =
          __expf(-(2.0f * (float)j0 / (float)dseg) * 9.210340371976184f);
      const float invf1 =
          __expf(-(2.0f * (float)(j0 + 1) / (float)dseg) * 9.210340371976184f);
#pragma unroll
      for (int mt = 0; mt < 4; mt++) {
        const int m = m0 + wr + mt * 16 + lm;
        const int bi = m >> 11, si = m & (S_ - 1);
        const int pos = pos_xyz[((size_t)bi * S_ + si) * 3 + axis];
        short4b pk;
#pragma unroll
        for (int u = 0; u < 2; u++) {
          const float ve = acc[nt][mt][2 * u], vo = acc[nt][mt][2 * u + 1];
          float sn, cs;
          sincosf((float)pos * (u ? invf1 : invf0), &sn, &cs);
          pk[2 * u]     = (short)f2bf(fmaf(ve, cs, -vo * sn) * osc);
          pk[2 * u + 1] = (short)f2bf(fmaf(vo, cs, ve * sn) * osc);
        }
        *(short4b*)(Dst + ((size_t)(bi * NH_ + h) * S_ + si) * HD_ + dbase) = pk;
      }
    }
  }
}

// ---------------------------------------------------------------------------
// Flash attention on MFMA. Block = (64 q-rows) x (b,h); 4 waves, each owns a
// 16-row q strip. K/V double-buffered in XOR-swizzled LDS via global_load_lds
// (prefetch at top of iter, drain at end-of-iter barrier). Softmax in base-2.
// Masking only on diagonal/len-tail tiles. Ps swizzled (stride 64) -> LDS =
// exactly 40960 B -> 4 blocks/CU, whole grid co-resident.
// Balanced qt permutation (66 tiles per CU under either block->CU grouping).
// DPP row_ror butterflies for softmax reductions (VALU, no LDS-pipe).
// NEW: defer-rescale (skip O-rescale while tile max grows <= 8 in base-2;
// P bounded by 2^8, bf16-safe) + s_setprio(1) around MFMA clusters.
// ---------------------------------------------------------------------------
__global__ __launch_bounds__(256) void flash_mfma(
    const unsigned short* __restrict__ Q, const unsigned short* __restrict__ Kg,
    const unsigned short* __restrict__ Vt, const int* __restrict__ lengths,
    unsigned short* __restrict__ Oa) {
  __shared__ __align__(16) unsigned short Ks[2 * 64 * 64];
  __shared__ __align__(16) unsigned short Vs[2 * 64 * 64];
  __shared__ __align__(16) unsigned short Ps[4][16 * 64];

  const int lin = blockIdx.y * gridDim.x + blockIdx.x;  // 0..1023
  const int xcd = lin & 7, k = lin >> 3;                // k 0..127 within XCD
  const int s = k >> 5, c = k & 31;
  const int pc = (c & 1) ? 31 - (c >> 1) : (c >> 1);    // pair permutation
  const int qt = (s & 1) ? 31 - pc : pc;
  const int bh = xcd * 4 + s;                           // 4 bh per XCD (L2)
  const int b = bh >> 4, h = bh & 15;
  const int q0 = qt * 64;

  const int w = threadIdx.x >> 6, lane = threadIdx.x & 63;
  const int lm = lane & 15, q4 = lane >> 4;
  const int len = lengths[b];
  const unsigned short* Qp = Q + (size_t)bh * S_ * HD_;
  const unsigned short* Kp = Kg + (size_t)bh * S_ * HD_;
  const unsigned short* Vp = Vt + (size_t)bh * HD_ * S_;

  // staging geometry: wave w stages tile rows [w*16, w*16+16), 8 rows/call.
  // lane -> (row offset r8, chunk c8); source chunk pre-swizzled: c8 ^ (row&7).
  const int r8 = lane >> 3, c8 = lane & 7;
  const int rs0 = w * 16 + r8, rs1 = rs0 + 8;           // (rs1&7) == (rs0&7)
  const int cs = (c8 ^ (rs0 & 7)) << 3;                 // chunk -> shorts
  const unsigned short* gK0 = Kp + (size_t)rs0 * HD_ + cs;
  const unsigned short* gK1 = Kp + (size_t)rs1 * HD_ + cs;
  const unsigned short* gV0 = Vp + (size_t)rs0 * S_ + cs;
  const unsigned short* gV1 = Vp + (size_t)rs1 * S_ + cs;
  unsigned short* dK0 = Ks + w * 16 * 64;
  unsigned short* dK1 = Ks + (w * 16 + 8) * 64;
  unsigned short* dV0 = Vs + w * 16 * 64;
  unsigned short* dV1 = Vs + (w * 16 + 8) * 64;

  const int qrow = q0 + w * 16 + lm;  // A-operand row for this lane
  short8 qf[2];
  qf[0] = *(const short8*)(Qp + (size_t)qrow * HD_ + q4 * 8);
  qf[1] = *(const short8*)(Qp + (size_t)qrow * HD_ + 32 + q4 * 8);

  const floatx4 z4 = {0.f, 0.f, 0.f, 0.f};
  floatx4 o[4];
#pragma unroll
  for (int dt = 0; dt < 4; dt++) o[dt] = z4;
  float m_i[4], l_i[4];
#pragma unroll
  for (int r = 0; r < 4; r++) { m_i[r] = -1e30f; l_i[r] = 0.0f; }

  unsigned short* ps = Ps[w];
  const int ktiles = min(qt + 1, (len + 63) >> 6);

  // prologue: stage tile 0 into buffer 0
  gl2lds16(gK0, dK0);
  gl2lds16(gK1, dK1);
  gl2lds16(gV0, dV0);
  gl2lds16(gV1, dV1);
  __syncthreads();

  int cur = 0;
  for (int kt = 0; kt < ktiles; kt++) {
    const int k0 = kt * 64;
    // issue next tile's staging into the other buffer (drains at the barrier)
    if (kt + 1 < ktiles) {
      const size_t koff = (size_t)(k0 + 64) * HD_;
      const int nb = (cur ^ 1) * 4096;
      gl2lds16(gK0 + koff, dK0 + nb);
      gl2lds16(gK1 + koff, dK1 + nb);
      gl2lds16(gV0 + (k0 + 64), dV0 + nb);
      gl2lds16(gV1 + (k0 + 64), dV1 + nb);
    }
    const unsigned short* kc = Ks + cur * 4096;
    const unsigned short* vc = Vs + cur * 4096;

    // S = Q K^T  (64 cols in 4 n-tiles); K frags from swizzled LDS.
    floatx4 sc[4];
    __builtin_amdgcn_s_setprio(1);
#pragma unroll
    for (int nt = 0; nt < 4; nt++) {
      const int row = nt * 16 + lm, sw = row & 7;
      const unsigned short* kb = kc + row * 64;
      const short8 b0 = *(const short8*)(kb + ((q4 ^ sw) << 3));
      const short8 b1 = *(const short8*)(kb + (((q4 + 4) ^ sw) << 3));
      sc[nt] = __builtin_amdgcn_mfma_f32_16x16x32_bf16(qf[0], b0, z4, 0, 0, 0);
      sc[nt] = __builtin_amdgcn_mfma_f32_16x16x32_bf16(qf[1], b1, sc[nt], 0, 0, 0);
    }
    __builtin_amdgcn_s_setprio(0);
    // mask only where it can trigger: diagonal tile or len-tail tile
    if (kt == qt || k0 + 64 > len) {
#pragma unroll
      for (int nt = 0; nt < 4; nt++) {
        const int col = k0 + nt * 16 + lm;
#pragma unroll
        for (int r = 0; r < 4; r++) {
          const int row = q0 + w * 16 + q4 * 4 + r;
          if (col > row || col >= len) sc[nt][r] = -1e30f;
        }
      }
    }
    // online softmax, base-2, deferred rescale (thr = 8 -> P <= 2^8)
    float mx[4];
#pragma unroll
    for (int r = 0; r < 4; r++) {
      float m0 = fmaxf(fmaxf(sc[0][r], sc[1][r]), fmaxf(sc[2][r], sc[3][r]));
      m0 = fmaxf(m0, dpp_ror<0x121>(m0));
      m0 = fmaxf(m0, dpp_ror<0x122>(m0));
      m0 = fmaxf(m0, dpp_ror<0x124>(m0));
      m0 = fmaxf(m0, dpp_ror<0x128>(m0));
      mx[r] = m0;
    }
    const bool ok = (mx[0] <= m_i[0] + 8.f) && (mx[1] <= m_i[1] + 8.f) &&
                    (mx[2] <= m_i[2] + 8.f) && (mx[3] <= m_i[3] + 8.f);
    if (!__all(ok)) {
#pragma unroll
      for (int r = 0; r < 4; r++) {
        const float mt = fmaxf(m_i[r], mx[r]);
        const float al = __ocml_native_exp2_f32(m_i[r] - mt);
        l_i[r] *= al;
        m_i[r] = mt;
#pragma unroll
        for (int dt = 0; dt < 4; dt++) o[dt][r] *= al;
      }
    }
#pragma unroll
    for (int r = 0; r < 4; r++) {
      float rs = 0.0f;
#pragma unroll
      for (int nt = 0; nt < 4; nt++) {
        const float pp = __ocml_native_exp2_f32(sc[nt][r] - m_i[r]);
        sc[nt][r] = pp;
        rs += pp;
      }
      rs += dpp_ror<0x121>(rs);
      rs += dpp_ror<0x122>(rs);
      rs += dpp_ror<0x124>(rs);
      rs += dpp_ror<0x128>(rs);
      l_i[r] += rs;
    }
    // P: D-layout -> bf16 -> wave-private LDS strip, stride 64 + chunk-XOR
    // swizzle; wave-private + in-order DS => no barrier needed.
#pragma unroll
    for (int nt = 0; nt < 4; nt++)
#pragma unroll
      for (int r = 0; r < 4; r++) {
        const int row = q4 * 4 + r;
        const int cc = (((nt * 2 + (lm >> 3)) ^ (row & 7)) << 3) | (lm & 7);
        ps[row * 64 + cc] = f2bf(sc[nt][r]);
      }
    // O += P V   (V^T rows are d; V frags from swizzled LDS)
    __builtin_amdgcn_s_setprio(1);
#pragma unroll
    for (int ks = 0; ks < 2; ks++) {
      const short8 pf = *(const short8*)(
          ps + lm * 64 + ((((ks << 2) + q4) ^ (lm & 7)) << 3));
#pragma unroll
      for (int dt = 0; dt < 4; dt++) {
        const int row = dt * 16 + lm, sw = row & 7;
        const short8 vf = *(const short8*)(
            vc + row * 64 + ((((ks << 2) + q4) ^ sw) << 3));
        o[dt] = __builtin_amdgcn_mfma_f32_16x16x32_bf16(pf, vf, o[dt], 0, 0, 0);
      }
    }
    __builtin_amdgcn_s_setprio(0);
    __syncthreads();  // drains next-tile staging; all waves done reading cur
    cur ^= 1;
  }
  // normalize + write attn (B,S,DM) bf16; col = h*64 + d
  float invl[4];
#pragma unroll
  for (int r = 0; r < 4; r++) invl[r] = 1.0f / l_i[r];
#pragma unroll
  for (int dt = 0; dt < 4; dt++)
#pragma unroll
    for (int r = 0; r < 4; r++) {
      const int row = q0 + w * 16 + q4 * 4 + r;
      const int col = h * HD_ + dt * 16 + lm;
      Oa[((size_t)b * S_ + row) * DM_ + col] = f2bf(o[dt][r] * invl[r]);
    }
}

// ---------------------------------------------------------------------------
// Out projection (bf16 MFMA): C[m][n] = sum_k A[m][k] * W[n][k], fp32 out.
// M=4096, N=1024, K=1024. Operands swapped so each thread holds 4 consecutive
// n at fixed m -> one float4 (16B) store per (nt,mt).
// ---------------------------------------------------------------------------
__global__ __launch_bounds__(256) void out_gemm(
    const unsigned short* __restrict__ A, const unsigned short* __restrict__ W,
    float* __restrict__ C) {
  __shared__ __align__(16) unsigned short As[128 * 32];
  __shared__ __align__(16) unsigned short Bs[128 * 32];
  const int m0 = blockIdx.y * 128, n0 = blockIdx.x * 128;
  const int w = threadIdx.x >> 6, lane = threadIdx.x & 63;
  const int lm = lane & 15, q4 = lane >> 4;
  const int srow = w * 32;
  const int r_in = lane >> 2, c_in = (lane & 3) * 8;
  const int wr = (w >> 1) * 64, wc = (w & 1) * 64;
  floatx4 acc[4][4];  // acc[nt][mt]: row <-> n, col <-> m
  const floatx4 z4 = {0.f, 0.f, 0.f, 0.f};
#pragma unroll
  for (int i = 0; i < 4; i++)
#pragma unroll
    for (int j = 0; j < 4; j++) acc[i][j] = z4;

  for (int k0 = 0; k0 < DM_; k0 += 32) {
    gl2lds16(A + (size_t)(m0 + srow + r_in) * DM_ + k0 + c_in, As + srow * 32);
    gl2lds16(A + (size_t)(m0 + srow + 16 + r_in) * DM_ + k0 + c_in,
             As + (srow + 16) * 32);
    gl2lds16(W + (size_t)(n0 + srow + r_in) * DM_ + k0 + c_in, Bs + srow * 32);
    gl2lds16(W + (size_t)(n0 + srow + 16 + r_in) * DM_ + k0 + c_in,
             Bs + (srow + 16) * 32);
    __syncthreads();
    short8 af[4], bf[4];
#pragma unroll
    for (int t = 0; t < 4; t++)
      af[t] = *(const short8*)(As + (wr + t * 16 + lm) * 32 + q4 * 8);
#pragma unroll
    for (int t = 0; t < 4; t++)
      bf[t] = *(const short8*)(Bs + (wc + t * 16 + lm) * 32 + q4 * 8);
#pragma unroll
    for (int i = 0; i < 4; i++)
#pragma unroll
      for (int j = 0; j < 4; j++)
        acc[i][j] =
            __builtin_amdgcn_mfma_f32_16x16x32_bf16(bf[i], af[j], acc[i][j],
                                                    0, 0, 0);
    __syncthreads();
  }
#pragma unroll
  for (int nt = 0; nt < 4; nt++) {
    const int nbase = n0 + wc + nt * 16 + q4 * 4;
#pragma unroll
    for (int mt = 0; mt < 4; mt++) {
      const int m = m0 + wr + mt * 16 + lm;
      *(floatx4*)(C + (size_t)m * DM_ + nbase) = acc[nt][mt];
    }
  }
}

}  // namespace

extern "C" void kernel_launch(void* const* d_in, const int* in_sizes, int n_in,
                              void* d_out, int out_size, void* d_ws, size_t ws_size,
                              hipStream_t stream) {
  const float* hidden = (const float*)d_in[0];          // (2,2048,1024) f32
  const float* w_qkv = (const float*)d_in[1];           // (3072,1024) f32
  const float* w_out = (const float*)d_in[2];           // (1024,1024) f32
  const unsigned char* amask = (const unsigned char*)d_in[3];  // (2,2048) bool
  const int* pos_xyz = (const int*)d_in[5];             // (2,2048,3) i32
  float* out = (float*)d_out;                           // (2,2048,1024) f32

  constexpr size_t NHID = (size_t)B_ * S_ * DM_;        // 4,194,304
  constexpr size_t NWQ = (size_t)3 * DM_ * DM_;         // 3,145,728
  constexpr size_t NWO = (size_t)DM_ * DM_;             // 1,048,576
  constexpr size_t NQKV = (size_t)B_ * NH_ * S_ * HD_;  // 4,194,304

  unsigned short* hb = (unsigned short*)d_ws;
  unsigned short* wqb = hb + NHID;
  unsigned short* wob = wqb + NWQ;
  unsigned short* Qb = wob + NWO;
  unsigned short* Kb = Qb + NQKV;
  unsigned short* Vtb = Kb + NQKV;
  unsigned short* attn = Vtb + NQKV;
  int* lens = (int*)(attn + NQKV);

  prep<<<dim3(4096 + B_), dim3(256), 0, stream>>>(hidden, w_qkv, w_out, amask,
                                                  hb, lens);
  qkv_gemm<<<dim3(3 * DM_ / 128, B_ * S_ / 128), dim3(256), 0, stream>>>(
      hb, wqb, pos_xyz, Qb, Kb, Vtb);
  flash_mfma<<<dim3(S_ / 64, B_ * NH_), dim3(256), 0, stream>>>(
      Qb, Kb, Vtb, lens, attn);
  out_gemm<<<dim3(DM_ / 128, B_ * S_ / 128), dim3(256), 0, stream>>>(
      attn, wob, out);
}

// Round 8
// 238.044 us; speedup vs baseline: 1.2119x; 1.0102x over previous
//
#include <hip/hip_runtime.h>
#include <math.h>

extern "C" __device__ float __ocml_native_exp2_f32(float);

namespace {

typedef __attribute__((ext_vector_type(8))) short short8;   // 8 bf16 = 4 VGPRs
typedef __attribute__((ext_vector_type(4))) short short4b;  // 4 bf16 = 8B store
typedef __attribute__((ext_vector_type(4))) float floatx4;  // MFMA C/D frag

constexpr int B_ = 2;
constexpr int S_ = 2048;
constexpr int DM_ = 1024;
constexpr int NH_ = 16;
constexpr int HD_ = 64;

// fp32 -> bf16 round-to-nearest-even
__device__ inline unsigned short f2bf(float f) {
  unsigned u = __builtin_bit_cast(unsigned, f);
  u += 0x7fffu + ((u >> 16) & 1u);
  return (unsigned short)(u >> 16);
}

// DPP row-rotate (within 16-lane rows) — reduction butterflies without LDS.
template <int CTRL>
__device__ inline float dpp_ror(float x) {
  const int r = __builtin_amdgcn_update_dpp(
      0, __builtin_bit_cast(int, x), CTRL, 0xF, 0xF, false);
  return __builtin_bit_cast(float, r);
}

// async global->LDS, 16B per lane; lds dest must be wave-uniform (lane i lands
// at lds + i*16).
__device__ inline void gl2lds16(const unsigned short* g, unsigned short* l) {
  __builtin_amdgcn_global_load_lds(
      (const __attribute__((address_space(1))) unsigned int*)g,
      (__attribute__((address_space(3))) unsigned int*)l, 16, 0, 0);
}

// ---------------------------------------------------------------------------
// Fused prep: one launch does all three f32->bf16 conversions (dsts are
// contiguous in workspace: hb | wqb | wob) + the 2 length reductions.
// ---------------------------------------------------------------------------
__global__ __launch_bounds__(256) void prep(
    const float* __restrict__ hidden, const float* __restrict__ wqkv,
    const float* __restrict__ wout, const unsigned char* __restrict__ mask,
    unsigned short* __restrict__ hb, int* __restrict__ lengths) {
  const int bid = blockIdx.x;
  if (bid < 4096) {
    const int i = bid * 256 + threadIdx.x;  // short8 index into combined dst
    const float* src;
    int off;
    if (i < 524288)              { src = hidden; off = 0; }
    else if (i < 524288 + 393216){ src = wqkv;   off = 524288; }
    else                         { src = wout;   off = 524288 + 393216; }
    const size_t j = (size_t)(i - off);
    const float4 a = ((const float4*)src)[j * 2];
    const float4 b = ((const float4*)src)[j * 2 + 1];
    short8 v;
    v[0] = (short)f2bf(a.x); v[1] = (short)f2bf(a.y);
    v[2] = (short)f2bf(a.z); v[3] = (short)f2bf(a.w);
    v[4] = (short)f2bf(b.x); v[5] = (short)f2bf(b.y);
    v[6] = (short)f2bf(b.z); v[7] = (short)f2bf(b.w);
    ((short8*)hb)[i] = v;
  } else {
    const int b = bid - 4096;
    const int es1 = (mask[1] != 0);  // byte-1 nonzero => 1-byte bool storage
    __shared__ int cnt;
    if (threadIdx.x == 0) cnt = 0;
    __syncthreads();
    int local = 0;
    for (int s = threadIdx.x; s < S_; s += blockDim.x) {
      bool nz;
      if (es1) nz = mask[b * S_ + s] != 0;
      else     nz = ((const unsigned int*)mask)[b * S_ + s] != 0;
      local += nz ? 1 : 0;
    }
    atomicAdd(&cnt, local);
    __syncthreads();
    if (threadIdx.x == 0) lengths[b] = cnt;
  }
}

// ---------------------------------------------------------------------------
// QKV GEMM (bf16 MFMA): C[m][n] = sum_k A[m][k] * W[n][k]
// M=4096, N=3072, K=1024. 128x128 tile, BK=32, 4 waves each 64x64.
// NEW: double-buffered LDS staging (prefetch tile k+1 while computing k; one
// barrier per iter) + chunk-XOR LDS swizzle (phys = chunk ^ ((row>>1)&3),
// applied on the pre-swizzled GLOBAL source and on the read chunk) -> the
// 64B-row-stride fragment reads spread over 8 banks (2-way = free).
// Coalesced epilogues: Q/K via swapped MFMA operands (RoPE in-register,
// 8B packed stores), V via packed 8B stores into V^T. q pre-scaled by
// 1/8*log2(e) for base-2 flash softmax.
// ---------------------------------------------------------------------------
__global__ __launch_bounds__(256) void qkv_gemm(
    const unsigned short* __restrict__ A, const unsigned short* __restrict__ W,
    const int* __restrict__ pos_xyz,
    unsigned short* __restrict__ Qb, unsigned short* __restrict__ Kb,
    unsigned short* __restrict__ Vtb) {
  __shared__ __align__(16) unsigned short As[2 * 128 * 32];
  __shared__ __align__(16) unsigned short Bs[2 * 128 * 32];
  const int m0 = blockIdx.y * 128, n0 = blockIdx.x * 128;
  const int w = threadIdx.x >> 6, lane = threadIdx.x & 63;
  const int lm = lane & 15, q4 = lane >> 4;
  const int srow = w * 32;                  // this wave's staging rows
  const int r_in = lane >> 2;               // 0..15
  const int c_sw = (((lane & 3) ^ ((r_in >> 1) & 3)) << 3);  // swizzled chunk
  const int wr = (w >> 1) * 64, wc = (w & 1) * 64;
  const int which = n0 >> 10;               // 0=Q 1=K 2=V (block-uniform)
  const int rsw = (lm >> 1) & 3;            // read-side swizzle sel
  floatx4 acc[4][4];
  const floatx4 z4 = {0.f, 0.f, 0.f, 0.f};
#pragma unroll
  for (int i = 0; i < 4; i++)
#pragma unroll
    for (int j = 0; j < 4; j++) acc[i][j] = z4;

  const unsigned short* gA0 = A + (size_t)(m0 + srow + r_in) * DM_ + c_sw;
  const unsigned short* gA1 = A + (size_t)(m0 + srow + 16 + r_in) * DM_ + c_sw;
  const unsigned short* gB0 = W + (size_t)(n0 + srow + r_in) * DM_ + c_sw;
  const unsigned short* gB1 = W + (size_t)(n0 + srow + 16 + r_in) * DM_ + c_sw;

  // prologue: stage k0=0 into buffer 0
  gl2lds16(gA0, As + srow * 32);
  gl2lds16(gA1, As + (srow + 16) * 32);
  gl2lds16(gB0, Bs + srow * 32);
  gl2lds16(gB1, Bs + (srow + 16) * 32);
  __syncthreads();

  int cur = 0;
  for (int k0 = 0; k0 < DM_; k0 += 32) {
    if (k0 + 32 < DM_) {
      const int nb = (cur ^ 1) * 4096;
      gl2lds16(gA0 + k0 + 32, As + nb + srow * 32);
      gl2lds16(gA1 + k0 + 32, As + nb + (srow + 16) * 32);
      gl2lds16(gB0 + k0 + 32, Bs + nb + srow * 32);
      gl2lds16(gB1 + k0 + 32, Bs + nb + (srow + 16) * 32);
    }
    const unsigned short* as = As + cur * 4096;
    const unsigned short* bs = Bs + cur * 4096;
    short8 af[4], bf[4];
#pragma unroll
    for (int t = 0; t < 4; t++)
      af[t] = *(const short8*)(as + (wr + t * 16 + lm) * 32 + ((q4 ^ rsw) << 3));
#pragma unroll
    for (int t = 0; t < 4; t++)
      bf[t] = *(const short8*)(bs + (wc + t * 16 + lm) * 32 + ((q4 ^ rsw) << 3));
    if (which == 2) {
      // acc[mt][nt]: row <-> m(si), col <-> n(d)
#pragma unroll
      for (int i = 0; i < 4; i++)
#pragma unroll
        for (int j = 0; j < 4; j++)
          acc[i][j] = __builtin_amdgcn_mfma_f32_16x16x32_bf16(af[i], bf[j],
                                                              acc[i][j], 0, 0, 0);
    } else {
      // swapped: acc[nt][mt]: row <-> n(d), col <-> m(si)
#pragma unroll
      for (int i = 0; i < 4; i++)
#pragma unroll
        for (int j = 0; j < 4; j++)
          acc[i][j] = __builtin_amdgcn_mfma_f32_16x16x32_bf16(bf[i], af[j],
                                                              acc[i][j], 0, 0, 0);
    }
    __syncthreads();  // drains next-tile staging; all waves done with cur
    cur ^= 1;
  }

  const int h = ((n0 + wc) & 1023) >> 6;  // wave-uniform head
  if (which == 2) {
#pragma unroll
    for (int nt = 0; nt < 4; nt++) {
      const int d = nt * 16 + lm;
#pragma unroll
      for (int mt = 0; mt < 4; mt++) {
        const int m = m0 + wr + mt * 16 + q4 * 4;
        const int bi = m >> 11, si = m & (S_ - 1);
        short4b pk;
#pragma unroll
        for (int r = 0; r < 4; r++) pk[r] = (short)f2bf(acc[mt][nt][r]);
        *(short4b*)(Vtb + ((size_t)(bi * NH_ + h) * HD_ + d) * S_ + si) = pk;
      }
    }
  } else {
    unsigned short* Dst = (which == 0) ? Qb : Kb;
    // q pre-scaled by 1/8 * log2(e) for base-2 flash softmax
    const float osc = (which == 0) ? 0.125f * 1.44269504088896f : 1.0f;
#pragma unroll
    for (int nt = 0; nt < 4; nt++) {
      const int dbase = nt * 16 + q4 * 4;  // even; both RoPE pairs in-register
      const int p0 = dbase >> 1;           // even -> p0,p0+1 share an axis
      int axis, j0, dseg;
      if (p0 < 10)      { axis = 0; j0 = p0;      dseg = 20; }
      else if (p0 < 20) { axis = 1; j0 = p0 - 10; dseg = 20; }
      else              { axis = 2; j0 = p0 - 20; dseg = 24; }
      // 10000^(-2j/dseg) = exp(-2j/dseg * ln 1e4)
      const float invf0 =
          __expf(-(2.0f * (float)j0 / (float)dseg) * 9.210340371976184f);
      const float invf1 =
          __expf(-(2.0f * (float)(j0 + 1) / (float)dseg) * 9.210340371976184f);
#pragma unroll
      for (int mt = 0; mt < 4; mt++) {
        const int m = m0 + wr + mt * 16 + lm;
        const int bi = m >> 11, si = m & (S_ - 1);
        const int pos = pos_xyz[((size_t)bi * S_ + si) * 3 + axis];
        short4b pk;
#pragma unroll
        for (int u = 0; u < 2; u++) {
          const float ve = acc[nt][mt][2 * u], vo = acc[nt][mt][2 * u + 1];
          float sn, cs;
          sincosf((float)pos * (u ? invf1 : invf0), &sn, &cs);
          pk[2 * u]     = (short)f2bf(fmaf(ve, cs, -vo * sn) * osc);
          pk[2 * u + 1] = (short)f2bf(fmaf(vo, cs, ve * sn) * osc);
        }
        *(short4b*)(Dst + ((size_t)(bi * NH_ + h) * S_ + si) * HD_ + dbase) = pk;
      }
    }
  }
}

// ---------------------------------------------------------------------------
// Flash attention on MFMA (unchanged from round 7, which verified).
// ---------------------------------------------------------------------------
__global__ __launch_bounds__(256) void flash_mfma(
    const unsigned short* __restrict__ Q, const unsigned short* __restrict__ Kg,
    const unsigned short* __restrict__ Vt, const int* __restrict__ lengths,
    unsigned short* __restrict__ Oa) {
  __shared__ __align__(16) unsigned short Ks[2 * 64 * 64];
  __shared__ __align__(16) unsigned short Vs[2 * 64 * 64];
  __shared__ __align__(16) unsigned short Ps[4][16 * 64];

  const int lin = blockIdx.y * gridDim.x + blockIdx.x;  // 0..1023
  const int xcd = lin & 7, k = lin >> 3;                // k 0..127 within XCD
  const int s = k >> 5, c = k & 31;
  const int pc = (c & 1) ? 31 - (c >> 1) : (c >> 1);    // pair permutation
  const int qt = (s & 1) ? 31 - pc : pc;
  const int bh = xcd * 4 + s;                           // 4 bh per XCD (L2)
  const int b = bh >> 4, h = bh & 15;
  const int q0 = qt * 64;

  const int w = threadIdx.x >> 6, lane = threadIdx.x & 63;
  const int lm = lane & 15, q4 = lane >> 4;
  const int len = lengths[b];
  const unsigned short* Qp = Q + (size_t)bh * S_ * HD_;
  const unsigned short* Kp = Kg + (size_t)bh * S_ * HD_;
  const unsigned short* Vp = Vt + (size_t)bh * HD_ * S_;

  const int r8 = lane >> 3, c8 = lane & 7;
  const int rs0 = w * 16 + r8, rs1 = rs0 + 8;           // (rs1&7) == (rs0&7)
  const int cs = (c8 ^ (rs0 & 7)) << 3;                 // chunk -> shorts
  const unsigned short* gK0 = Kp + (size_t)rs0 * HD_ + cs;
  const unsigned short* gK1 = Kp + (size_t)rs1 * HD_ + cs;
  const unsigned short* gV0 = Vp + (size_t)rs0 * S_ + cs;
  const unsigned short* gV1 = Vp + (size_t)rs1 * S_ + cs;
  unsigned short* dK0 = Ks + w * 16 * 64;
  unsigned short* dK1 = Ks + (w * 16 + 8) * 64;
  unsigned short* dV0 = Vs + w * 16 * 64;
  unsigned short* dV1 = Vs + (w * 16 + 8) * 64;

  const int qrow = q0 + w * 16 + lm;  // A-operand row for this lane
  short8 qf[2];
  qf[0] = *(const short8*)(Qp + (size_t)qrow * HD_ + q4 * 8);
  qf[1] = *(const short8*)(Qp + (size_t)qrow * HD_ + 32 + q4 * 8);

  const floatx4 z4 = {0.f, 0.f, 0.f, 0.f};
  floatx4 o[4];
#pragma unroll
  for (int dt = 0; dt < 4; dt++) o[dt] = z4;
  float m_i[4], l_i[4];
#pragma unroll
  for (int r = 0; r < 4; r++) { m_i[r] = -1e30f; l_i[r] = 0.0f; }

  unsigned short* ps = Ps[w];
  const int ktiles = min(qt + 1, (len + 63) >> 6);

  // prologue: stage tile 0 into buffer 0
  gl2lds16(gK0, dK0);
  gl2lds16(gK1, dK1);
  gl2lds16(gV0, dV0);
  gl2lds16(gV1, dV1);
  __syncthreads();

  int cur = 0;
  for (int kt = 0; kt < ktiles; kt++) {
    const int k0 = kt * 64;
    if (kt + 1 < ktiles) {
      const size_t koff = (size_t)(k0 + 64) * HD_;
      const int nb = (cur ^ 1) * 4096;
      gl2lds16(gK0 + koff, dK0 + nb);
      gl2lds16(gK1 + koff, dK1 + nb);
      gl2lds16(gV0 + (k0 + 64), dV0 + nb);
      gl2lds16(gV1 + (k0 + 64), dV1 + nb);
    }
    const unsigned short* kc = Ks + cur * 4096;
    const unsigned short* vc = Vs + cur * 4096;

    // S = Q K^T  (64 cols in 4 n-tiles); K frags from swizzled LDS.
    floatx4 sc[4];
    __builtin_amdgcn_s_setprio(1);
#pragma unroll
    for (int nt = 0; nt < 4; nt++) {
      const int row = nt * 16 + lm, sw = row & 7;
      const unsigned short* kb = kc + row * 64;
      const short8 b0 = *(const short8*)(kb + ((q4 ^ sw) << 3));
      const short8 b1 = *(const short8*)(kb + (((q4 + 4) ^ sw) << 3));
      sc[nt] = __builtin_amdgcn_mfma_f32_16x16x32_bf16(qf[0], b0, z4, 0, 0, 0);
      sc[nt] = __builtin_amdgcn_mfma_f32_16x16x32_bf16(qf[1], b1, sc[nt], 0, 0, 0);
    }
    __builtin_amdgcn_s_setprio(0);
    // mask only where it can trigger: diagonal tile or len-tail tile
    if (kt == qt || k0 + 64 > len) {
#pragma unroll
      for (int nt = 0; nt < 4; nt++) {
        const int col = k0 + nt * 16 + lm;
#pragma unroll
        for (int r = 0; r < 4; r++) {
          const int row = q0 + w * 16 + q4 * 4 + r;
          if (col > row || col >= len) sc[nt][r] = -1e30f;
        }
      }
    }
    // online softmax, base-2, deferred rescale (thr = 8 -> P <= 2^8)
    float mx[4];
#pragma unroll
    for (int r = 0; r < 4; r++) {
      float m0 = fmaxf(fmaxf(sc[0][r], sc[1][r]), fmaxf(sc[2][r], sc[3][r]));
      m0 = fmaxf(m0, dpp_ror<0x121>(m0));
      m0 = fmaxf(m0, dpp_ror<0x122>(m0));
      m0 = fmaxf(m0, dpp_ror<0x124>(m0));
      m0 = fmaxf(m0, dpp_ror<0x128>(m0));
      mx[r] = m0;
    }
    const bool ok = (mx[0] <= m_i[0] + 8.f) && (mx[1] <= m_i[1] + 8.f) &&
                    (mx[2] <= m_i[2] + 8.f) && (mx[3] <= m_i[3] + 8.f);
    if (!__all(ok)) {
#pragma unroll
      for (int r = 0; r < 4; r++) {
        const float mt = fmaxf(m_i[r], mx[r]);
        const float al = __ocml_native_exp2_f32(m_i[r] - mt);
        l_i[r] *= al;
        m_i[r] = mt;
#pragma unroll
        for (int dt = 0; dt < 4; dt++) o[dt][r] *= al;
      }
    }
#pragma unroll
    for (int r = 0; r < 4; r++) {
      float rs = 0.0f;
#pragma unroll
      for (int nt = 0; nt < 4; nt++) {
        const float pp = __ocml_native_exp2_f32(sc[nt][r] - m_i[r]);
        sc[nt][r] = pp;
        rs += pp;
      }
      rs += dpp_ror<0x121>(rs);
      rs += dpp_ror<0x122>(rs);
      rs += dpp_ror<0x124>(rs);
      rs += dpp_ror<0x128>(rs);
      l_i[r] += rs;
    }
    // P: D-layout -> bf16 -> wave-private LDS strip, stride 64 + chunk-XOR
#pragma unroll
    for (int nt = 0; nt < 4; nt++)
#pragma unroll
      for (int r = 0; r < 4; r++) {
        const int row = q4 * 4 + r;
        const int cc = (((nt * 2 + (lm >> 3)) ^ (row & 7)) << 3) | (lm & 7);
        ps[row * 64 + cc] = f2bf(sc[nt][r]);
      }
    // O += P V   (V^T rows are d; V frags from swizzled LDS)
    __builtin_amdgcn_s_setprio(1);
#pragma unroll
    for (int ks = 0; ks < 2; ks++) {
      const short8 pf = *(const short8*)(
          ps + lm * 64 + ((((ks << 2) + q4) ^ (lm & 7)) << 3));
#pragma unroll
      for (int dt = 0; dt < 4; dt++) {
        const int row = dt * 16 + lm, sw = row & 7;
        const short8 vf = *(const short8*)(
            vc + row * 64 + ((((ks << 2) + q4) ^ sw) << 3));
        o[dt] = __builtin_amdgcn_mfma_f32_16x16x32_bf16(pf, vf, o[dt], 0, 0, 0);
      }
    }
    __builtin_amdgcn_s_setprio(0);
    __syncthreads();  // drains next-tile staging; all waves done reading cur
    cur ^= 1;
  }
  // normalize + write attn (B,S,DM) bf16; col = h*64 + d
  float invl[4];
#pragma unroll
  for (int r = 0; r < 4; r++) invl[r] = 1.0f / l_i[r];
#pragma unroll
  for (int dt = 0; dt < 4; dt++)
#pragma unroll
    for (int r = 0; r < 4; r++) {
      const int row = q0 + w * 16 + q4 * 4 + r;
      const int col = h * HD_ + dt * 16 + lm;
      Oa[((size_t)b * S_ + row) * DM_ + col] = f2bf(o[dt][r] * invl[r]);
    }
}

// ---------------------------------------------------------------------------
// Out projection (bf16 MFMA): C[m][n] = sum_k A[m][k] * W[n][k], fp32 out.
// M=4096, N=1024, K=1024. Swapped operands -> float4 stores. Same dbuf +
// chunk-XOR swizzle as qkv_gemm.
// ---------------------------------------------------------------------------
__global__ __launch_bounds__(256) void out_gemm(
    const unsigned short* __restrict__ A, const unsigned short* __restrict__ W,
    float* __restrict__ C) {
  __shared__ __align__(16) unsigned short As[2 * 128 * 32];
  __shared__ __align__(16) unsigned short Bs[2 * 128 * 32];
  const int m0 = blockIdx.y * 128, n0 = blockIdx.x * 128;
  const int w = threadIdx.x >> 6, lane = threadIdx.x & 63;
  const int lm = lane & 15, q4 = lane >> 4;
  const int srow = w * 32;
  const int r_in = lane >> 2;
  const int c_sw = (((lane & 3) ^ ((r_in >> 1) & 3)) << 3);
  const int wr = (w >> 1) * 64, wc = (w & 1) * 64;
  const int rsw = (lm >> 1) & 3;
  floatx4 acc[4][4];  // acc[nt][mt]: row <-> n, col <-> m
  const floatx4 z4 = {0.f, 0.f, 0.f, 0.f};
#pragma unroll
  for (int i = 0; i < 4; i++)
#pragma unroll
    for (int j = 0; j < 4; j++) acc[i][j] = z4;

  const unsigned short* gA0 = A + (size_t)(m0 + srow + r_in) * DM_ + c_sw;
  const unsigned short* gA1 = A + (size_t)(m0 + srow + 16 + r_in) * DM_ + c_sw;
  const unsigned short* gB0 = W + (size_t)(n0 + srow + r_in) * DM_ + c_sw;
  const unsigned short* gB1 = W + (size_t)(n0 + srow + 16 + r_in) * DM_ + c_sw;

  gl2lds16(gA0, As + srow * 32);
  gl2lds16(gA1, As + (srow + 16) * 32);
  gl2lds16(gB0, Bs + srow * 32);
  gl2lds16(gB1, Bs + (srow + 16) * 32);
  __syncthreads();

  int cur = 0;
  for (int k0 = 0; k0 < DM_; k0 += 32) {
    if (k0 + 32 < DM_) {
      const int nb = (cur ^ 1) * 4096;
      gl2lds16(gA0 + k0 + 32, As + nb + srow * 32);
      gl2lds16(gA1 + k0 + 32, As + nb + (srow + 16) * 32);
      gl2lds16(gB0 + k0 + 32, Bs + nb + srow * 32);
      gl2lds16(gB1 + k0 + 32, Bs + nb + (srow + 16) * 32);
    }
    const unsigned short* as = As + cur * 4096;
    const unsigned short* bs = Bs + cur * 4096;
    short8 af[4], bf[4];
#pragma unroll
    for (int t = 0; t < 4; t++)
      af[t] = *(const short8*)(as + (wr + t * 16 + lm) * 32 + ((q4 ^ rsw) << 3));
#pragma unroll
    for (int t = 0; t < 4; t++)
      bf[t] = *(const short8*)(bs + (wc + t * 16 + lm) * 32 + ((q4 ^ rsw) << 3));
#pragma unroll
    for (int i = 0; i < 4; i++)
#pragma unroll
      for (int j = 0; j < 4; j++)
        acc[i][j] =
            __builtin_amdgcn_mfma_f32_16x16x32_bf16(bf[i], af[j], acc[i][j],
                                                    0, 0, 0);
    __syncthreads();
    cur ^= 1;
  }
#pragma unroll
  for (int nt = 0; nt < 4; nt++) {
    const int nbase = n0 + wc + nt * 16 + q4 * 4;
#pragma unroll
    for (int mt = 0; mt < 4; mt++) {
      const int m = m0 + wr + mt * 16 + lm;
      *(floatx4*)(C + (size_t)m * DM_ + nbase) = acc[nt][mt];
    }
  }
}

}  // namespace

extern "C" void kernel_launch(void* const* d_in, const int* in_sizes, int n_in,
                              void* d_out, int out_size, void* d_ws, size_t ws_size,
                              hipStream_t stream) {
  const float* hidden = (const float*)d_in[0];          // (2,2048,1024) f32
  const float* w_qkv = (const float*)d_in[1];           // (3072,1024) f32
  const float* w_out = (const float*)d_in[2];           // (1024,1024) f32
  const unsigned char* amask = (const unsigned char*)d_in[3];  // (2,2048) bool
  const int* pos_xyz = (const int*)d_in[5];             // (2,2048,3) i32
  float* out = (float*)d_out;                           // (2,2048,1024) f32

  constexpr size_t NHID = (size_t)B_ * S_ * DM_;        // 4,194,304
  constexpr size_t NWQ = (size_t)3 * DM_ * DM_;         // 3,145,728
  constexpr size_t NWO = (size_t)DM_ * DM_;             // 1,048,576
  constexpr size_t NQKV = (size_t)B_ * NH_ * S_ * HD_;  // 4,194,304

  unsigned short* hb = (unsigned short*)d_ws;
  unsigned short* wqb = hb + NHID;
  unsigned short* wob = wqb + NWQ;
  unsigned short* Qb = wob + NWO;
  unsigned short* Kb = Qb + NQKV;
  unsigned short* Vtb = Kb + NQKV;
  unsigned short* attn = Vtb + NQKV;
  int* lens = (int*)(attn + NQKV);

  prep<<<dim3(4096 + B_), dim3(256), 0, stream>>>(hidden, w_qkv, w_out, amask,
                                                  hb, lens);
  qkv_gemm<<<dim3(3 * DM_ / 128, B_ * S_ / 128), dim3(256), 0, stream>>>(
      hb, wqb, pos_xyz, Qb, Kb, Vtb);
  flash_mfma<<<dim3(S_ / 64, B_ * NH_), dim3(256), 0, stream>>>(
      Qb, Kb, Vtb, lens, attn);
  out_gemm<<<dim3(DM_ / 128, B_ * S_ / 128), dim3(256), 0, stream>>>(
      attn, wob, out);
}